// Round 1
// baseline (144.588 us; speedup 1.0000x reference)
//
#include <hip/hip_runtime.h>
#include <hip/hip_bf16.h>

#define BB 8
#define CC 256
#define HH 64
#define WW 64
#define NHEADS 8
#define LL 1024   // 32*32 after stride-2 conv
#define CH2 2048  // C*HEADS

typedef __bf16 bf16;
typedef __bf16 bf16x8 __attribute__((ext_vector_type(8)));
typedef float f32x4 __attribute__((ext_vector_type(4)));

// ---------------- Kernel A1: q/k grouped conv projection -> P[b][2048][1024] bf16
// block: (g, b), 256 threads. Conv out channel o = 8g+j uses input channel g.
__global__ __launch_bounds__(256) void proj_qk(const float* __restrict__ in,
    const float* __restrict__ w, const float* __restrict__ bias,
    bf16* __restrict__ out) {
  int g = blockIdx.x;
  int b = blockIdx.y;
  int t = threadIdx.x;
  __shared__ float ch[4096];  // one 64x64 input channel
  {
    const float4* src = reinterpret_cast<const float4*>(in + ((size_t)b*CC + g)*4096);
    float4* dst = reinterpret_cast<float4*>(ch);
#pragma unroll
    for (int i = 0; i < 4; i++) dst[t + i*256] = src[t + i*256];
  }
  float wj[8][4]; float bj[8];
#pragma unroll
  for (int j = 0; j < 8; j++) {
    float4 wv = reinterpret_cast<const float4*>(w)[g*8 + j];
    wj[j][0] = wv.x; wj[j][1] = wv.y; wj[j][2] = wv.z; wj[j][3] = wv.w;
    bj[j] = bias[g*8 + j];
  }
  __syncthreads();
#pragma unroll
  for (int li = 0; li < 4; li++) {
    int l = li*256 + t;
    int m = l >> 5, n = l & 31;
    int base = (m*64 + n)*2;     // (2m)*64 + 2n
    float c00 = ch[base], c01 = ch[base + 1];
    float c10 = ch[base + 64], c11 = ch[base + 65];
#pragma unroll
    for (int j = 0; j < 8; j++) {
      float v = bj[j] + wj[j][0]*c00 + wj[j][1]*c01 + wj[j][2]*c10 + wj[j][3]*c11;
      out[((size_t)b*CH2 + g*8 + j)*LL + l] = (bf16)v;
    }
  }
}

// ---------------- Kernel A2: v projection, TRANSPOSED store: Vt[b][h][l][c] bf16
// block: (m, h, b), 256 threads; thread t owns within-head channel c=t.
__global__ __launch_bounds__(256) void proj_v(const float* __restrict__ in,
    const float* __restrict__ w, const float* __restrict__ bias,
    bf16* __restrict__ outT) {
  int m = blockIdx.x;   // 0..31 (output spatial row)
  int h = blockIdx.y;
  int b = blockIdx.z;
  int t = threadIdx.x;
  __shared__ float ch[32*2*66];  // [g_local][ky][64 + 2 pad]
  {
    int seg = t >> 2, part = t & 3;     // 64 segments = (g_local, ky)
    int gl = seg >> 1, ky = seg & 1;
    const float* src = in + (((size_t)b*CC + h*32 + gl)*HH + (2*m + ky))*WW;
    float* drow = ch + (gl*2 + ky)*66;
#pragma unroll
    for (int i = 0; i < 4; i++) {
      float4 v = reinterpret_cast<const float4*>(src)[part + i*4];
      int x0 = (part + i*4)*4;
      drow[x0] = v.x; drow[x0+1] = v.y; drow[x0+2] = v.z; drow[x0+3] = v.w;
    }
  }
  __syncthreads();
  int c = t;
  int o = h*256 + c;          // conv output channel
  float4 wv = reinterpret_cast<const float4*>(w)[o];
  float bb = bias[o];
  int gl = c >> 3;            // g_local = (o>>3) - h*32
  const float* r0 = ch + (gl*2 + 0)*66;
  const float* r1 = ch + (gl*2 + 1)*66;
  bf16* dst = outT + (((size_t)b*NHEADS + h)*LL + m*32)*256 + c;
#pragma unroll
  for (int n = 0; n < 32; n++) {
    float v = bb + wv.x*r0[2*n] + wv.y*r0[2*n+1] + wv.z*r1[2*n] + wv.w*r1[2*n+1];
    dst[n*256] = (bf16)v;
  }
}

// ---------------- Kernel B: S = Q K^T (K=1024), softmax rows -> Pattn[b,h,c,d] bf16
// block: (tb, h, b) = 64 rows of c; 4 waves x 16 rows. MFMA 16x16x32.
__global__ __launch_bounds__(256) void attn_qk(const bf16* __restrict__ Pq,
    const bf16* __restrict__ Pk, bf16* __restrict__ Pattn) {
  int tb = blockIdx.x, h = blockIdx.y, b = blockIdx.z;
  int bh = b*NHEADS + h;
  int t = threadIdx.x;
  int wave = t >> 6, lane = t & 63;
  int lg = lane >> 4, lr = lane & 15;
  __shared__ bf16 Kl[256*40];   // 32-chunk of K, row pad to 40 (80B stride)
  __shared__ bf16 Ql[64*40];
  const bf16* Qb = Pq + ((size_t)bh*256 + tb*64)*LL;
  const bf16* Kb = Pk + (size_t)bh*256*LL;
  f32x4 acc[16];
#pragma unroll
  for (int i = 0; i < 16; i++) { f32x4 z = {0.f,0.f,0.f,0.f}; acc[i] = z; }
  for (int kb = 0; kb < 32; kb++) {
    __syncthreads();
    {
      const float4* src = reinterpret_cast<const float4*>(Kb + (size_t)t*LL + kb*32);
      float4* dstk = reinterpret_cast<float4*>(Kl + t*40);
#pragma unroll
      for (int i = 0; i < 4; i++) dstk[i] = src[i];
      int qr = t >> 2, part = t & 3;
      reinterpret_cast<float4*>(Ql + qr*40)[part] =
          reinterpret_cast<const float4*>(Qb + (size_t)qr*LL + kb*32)[part];
    }
    __syncthreads();
    bf16x8 af = *reinterpret_cast<const bf16x8*>(Ql + (wave*16 + lr)*40 + lg*8);
#pragma unroll
    for (int jt = 0; jt < 16; jt++) {
      bf16x8 bfv = *reinterpret_cast<const bf16x8*>(Kl + (jt*16 + lr)*40 + lg*8);
      acc[jt] = __builtin_amdgcn_mfma_f32_16x16x32_bf16(af, bfv, acc[jt], 0, 0, 0);
    }
  }
  // softmax over columns d (16 jt tiles x 16 lr lanes), scale = 1/sqrt(1024)
  const float scale = 0.03125f;
#pragma unroll
  for (int r = 0; r < 4; r++) {
    float mx = -1e30f;
#pragma unroll
    for (int jt = 0; jt < 16; jt++) mx = fmaxf(mx, acc[jt][r]);
#pragma unroll
    for (int off = 1; off < 16; off <<= 1) mx = fmaxf(mx, __shfl_xor(mx, off, 64));
    float sum = 0.f;
#pragma unroll
    for (int jt = 0; jt < 16; jt++) {
      float p = __expf(scale*(acc[jt][r] - mx));
      acc[jt][r] = p; sum += p;
    }
#pragma unroll
    for (int off = 1; off < 16; off <<= 1) sum += __shfl_xor(sum, off, 64);
    float inv = 1.f / sum;
    int c = tb*64 + wave*16 + lg*4 + r;
    bf16* orow = Pattn + ((size_t)bh*256 + c)*256;
#pragma unroll
    for (int jt = 0; jt < 16; jt++) orow[jt*16 + lr] = (bf16)(acc[jt][r]*inv);
  }
}

// ---------------- Kernel C: O = Pattn * V (K=256), fused deconv + bias + residual
// block: (mb, tb, bh). c rows tb*64..+64, l cols mb*256..+256.
__global__ __launch_bounds__(256) void pv_deconv(const bf16* __restrict__ Pattn,
    const bf16* __restrict__ Vt, const float* __restrict__ qin,
    const float* __restrict__ wo, const float* __restrict__ bo,
    const float* __restrict__ gamma, float* __restrict__ outp) {
  int mb = blockIdx.x, tb = blockIdx.y, bh = blockIdx.z;
  int h = bh & 7, b = bh >> 3;
  int t = threadIdx.x;
  int wave = t >> 6, lane = t & 63;
  int lg = lane >> 4, lr = lane & 15;
  __shared__ __attribute__((aligned(16))) char smem[64*260*2]; // union
  bf16* Pl = reinterpret_cast<bf16*>(smem);           // 64*40*2   = 5120B
  bf16* Vl = reinterpret_cast<bf16*>(smem + 5120);    // 256*40*2  = 20480B
  bf16* Ol = reinterpret_cast<bf16*>(smem);           // 64 x 260  (after MFMA)
  __shared__ float wo_s[256];
  __shared__ float bo_s[8];
  {
    int ct = t >> 5, rest = t & 31;
    wo_s[t] = wo[((size_t)(h*32 + tb*8 + ct))*32 + rest];
    if (t < 8) bo_s[t] = bo[h*32 + tb*8 + t];
  }
  const bf16* Pb = Pattn + ((size_t)bh*256 + tb*64)*256;
  const bf16* Vb = Vt + ((size_t)bh*LL + mb*256)*256;
  f32x4 acc[16];
#pragma unroll
  for (int i = 0; i < 16; i++) { f32x4 z = {0.f,0.f,0.f,0.f}; acc[i] = z; }
  for (int kb = 0; kb < 8; kb++) {
    __syncthreads();
    {
      int pr = t >> 2, part = t & 3;
      reinterpret_cast<float4*>(Pl + pr*40)[part] =
          reinterpret_cast<const float4*>(Pb + (size_t)pr*256 + kb*32)[part];
      const float4* vs = reinterpret_cast<const float4*>(Vb + (size_t)t*256 + kb*32);
      float4* vd = reinterpret_cast<float4*>(Vl + t*40);
#pragma unroll
      for (int i = 0; i < 4; i++) vd[i] = vs[i];
    }
    __syncthreads();
    bf16x8 af = *reinterpret_cast<const bf16x8*>(Pl + (wave*16 + lr)*40 + lg*8);
#pragma unroll
    for (int lt = 0; lt < 16; lt++) {
      bf16x8 bfv = *reinterpret_cast<const bf16x8*>(Vl + (lt*16 + lr)*40 + lg*8);
      acc[lt] = __builtin_amdgcn_mfma_f32_16x16x32_bf16(af, bfv, acc[lt], 0, 0, 0);
    }
  }
  __syncthreads();   // all MFMA LDS reads done before Ol overwrites
#pragma unroll
  for (int lt = 0; lt < 16; lt++) {
    int cl = wave*16 + lg*4;
#pragma unroll
    for (int r = 0; r < 4; r++) Ol[(cl + r)*260 + lt*16 + lr] = (bf16)acc[lt][r];
  }
  __syncthreads();
  float gm = gamma[0];
#pragma unroll
  for (int it = 0; it < 32; it++) {
    int flat = it*256 + t;                 // 8 ct x 16 y x 64 x
    int x = flat & 63, y = (flat >> 6) & 15, ct = flat >> 10;
    int n = x >> 1, s = x & 1, ml = y >> 1, r = y & 1;
    int ll = ml*32 + n;
    float v = bo_s[ct];
    const float* wrow = wo_s + ct*32 + (1 - r)*2 + (1 - s);
#pragma unroll
    for (int j = 0; j < 8; j++)
      v += wrow[j*4] * (float)Ol[(ct*8 + j)*260 + ll];
    int co = h*32 + tb*8 + ct;
    size_t oi = (((size_t)b*CC + co)*HH + (mb*16 + y))*WW + x;
    outp[oi] = qin[oi] + gm*v;
  }
}

extern "C" void kernel_launch(void* const* d_in, const int* in_sizes, int n_in,
                              void* d_out, int out_size, void* d_ws, size_t ws_size,
                              hipStream_t stream) {
  const float* q  = (const float*)d_in[0];
  const float* k  = (const float*)d_in[1];
  const float* v  = (const float*)d_in[2];
  const float* wq = (const float*)d_in[3];
  const float* bq = (const float*)d_in[4];
  const float* wk = (const float*)d_in[5];
  const float* bk = (const float*)d_in[6];
  const float* wv = (const float*)d_in[7];
  const float* bv = (const float*)d_in[8];
  const float* wo = (const float*)d_in[9];
  const float* bo = (const float*)d_in[10];
  const float* gamma = (const float*)d_in[11];
  float* out = (float*)d_out;

  char* ws = (char*)d_ws;
  bf16* Pq    = (bf16*)(ws);              //  33,554,432 B
  bf16* Pk    = (bf16*)(ws + 33554432);   //  33,554,432 B
  bf16* Vt    = (bf16*)(ws + 67108864);   //  33,554,432 B  [b][h][l][c]
  bf16* Pattn = (bf16*)(ws + 100663296);  //   8,388,608 B  [b][h][c][d]

  proj_qk<<<dim3(256, 8, 1), 256, 0, stream>>>(q, wq, bq, Pq);
  proj_qk<<<dim3(256, 8, 1), 256, 0, stream>>>(k, wk, bk, Pk);
  proj_v <<<dim3(32, 8, 8), 256, 0, stream>>>(v, wv, bv, Vt);
  attn_qk<<<dim3(4, 8, 8), 256, 0, stream>>>(Pq, Pk, Pattn);
  pv_deconv<<<dim3(4, 4, 64), 256, 0, stream>>>(Pattn, Vt, q, wo, bo, gamma, out);
}